// Round 10
// baseline (245.558 us; speedup 1.0000x reference)
//
#include <hip/hip_runtime.h>
#include <hip/hip_bf16.h>
#include <string.h>

#define L 4096
#define D 256
#define H 8
#define DH 32

typedef __attribute__((ext_vector_type(8))) short bf16x8;
typedef __attribute__((ext_vector_type(4))) float f32x4;

#define LOG2E 1.4426950408889634f
#define RS (0.17677669529663688f * LOG2E)   // 1/sqrt(DH) * log2(e), folded into Q

__device__ __forceinline__ ushort f2bf(float f) {
    union { float f; unsigned int i; } v; v.f = f;
    unsigned int x = v.i;
    return (ushort)((x + 0x7fffu + ((x >> 16) & 1u)) >> 16);   // RNE
}
__device__ __forceinline__ bf16x8 cvt8(const float* p) {
    float4 a = *(const float4*)p;
    float4 b = *(const float4*)(p + 4);
    bf16x8 r;
    r[0] = (short)f2bf(a.x); r[1] = (short)f2bf(a.y);
    r[2] = (short)f2bf(a.z); r[3] = (short)f2bf(a.w);
    r[4] = (short)f2bf(b.x); r[5] = (short)f2bf(b.y);
    r[6] = (short)f2bf(b.z); r[7] = (short)f2bf(b.w);
    return r;
}
// pack two fp32 -> bf16x2 dword; native v_cvt_pk_bf16_f32 on gfx950
__device__ __forceinline__ unsigned int pkbf(float a, float b) {
    float2 t; t.x = a; t.y = b;
    __hip_bfloat162 r = __float22bfloat162_rn(t);
    unsigned int u; memcpy(&u, &r, 4);
    return u;
}

// sigma: logical key u (0..63) -> K storage row within its 64-block.
__device__ __forceinline__ int ksig(int u) {
    return 32 * (u >> 5) + 16 * ((u >> 2) & 1) + 4 * ((u >> 3) & 3) + (u & 3);
}

// ---------------- Kernel 0: prepack ----------------
__global__ __launch_bounds__(256) void pack_kernel(
        const int* __restrict__ mask, const float* __restrict__ x,
        const float* __restrict__ wi, const float* __restrict__ wo,
        unsigned int* __restrict__ m2, ushort* __restrict__ xb,
        ushort* __restrict__ wib, ushort* __restrict__ wob)
{
    const int b = blockIdx.x;
    const int tid = threadIdx.x;
    if (b < 512) {
        __shared__ unsigned int rb[8 * 1025];
        const int4* src = (const int4*)(mask + (size_t)b * 8 * 4096);
#pragma unroll
        for (int i = 0; i < 32; i++) {
            const int g = i * 256 + tid;
            int4 v = src[g];
            rb[(g >> 10) * 1025 + (g & 1023)] =
                ((unsigned int)(v.x & 15) << 4)  | ((unsigned int)(v.y & 15) << 12) |
                ((unsigned int)(v.z & 15) << 20) | ((unsigned int)(v.w & 15) << 28);
        }
        __syncthreads();
        const int t = b >> 1, half = b & 1;
#pragma unroll
        for (int i = 0; i < 32; i++) {
            const int dd = i * 256 + tid;
            const int nt = dd & 3, s = (dd >> 2) & 7, qd = (dd >> 5) & 3, kt = dd >> 7;
            const unsigned int w =
                rb[s * 1025 + kt * 16 + 8 * (nt >> 1) + 2 * qd + (nt & 1)];
            m2[(size_t)t * 16384 + kt * 256 + (qd * 16 + 8 * half + s) * 4 + nt] = w;
        }
    } else if (b < 1024) {
        const int t = (b - 512) * 256 + tid;
        ((bf16x8*)xb)[t] = cvt8(x + t * 8);
    } else if (b < 1120) {
        const int t = (b - 1024) * 256 + tid;
        ((bf16x8*)wib)[t] = cvt8(wi + t * 8);
    } else {
        const int t = (b - 1120) * 256 + tid;
        ((bf16x8*)wob)[t] = cvt8(wo + t * 8);
    }
}

// ---------------- Kernel 1: QKV projection ----------------
__global__ __launch_bounds__(256) void qkv_kernel(
        const ushort* __restrict__ xb, const ushort* __restrict__ wb,
        const float* __restrict__ b,
        ushort* __restrict__ Qb, ushort* __restrict__ Kb, ushort* __restrict__ Vt)
{
    const int lane = threadIdx.x & 63, wv = threadIdx.x >> 6;
    const int quad = lane >> 4, l15 = lane & 15;
    const int m0 = blockIdx.x * 64 + wv * 16;
    const int n0 = blockIdx.y * 64;

    f32x4 acc[4] = {};
    for (int ks = 0; ks < 8; ks++) {
        const int kd = ks * 32 + quad * 8;
        bf16x8 af = *(const bf16x8*)(xb + (m0 + l15) * D + kd);
#pragma unroll
        for (int nt = 0; nt < 4; nt++) {
            bf16x8 bfr = *(const bf16x8*)(wb + (n0 + nt * 16 + l15) * D + kd);
            acc[nt] = __builtin_amdgcn_mfma_f32_16x16x32_bf16(af, bfr, acc[nt], 0, 0, 0);
        }
    }
#pragma unroll
    for (int nt = 0; nt < 4; nt++) {
        const int j = n0 + nt * 16 + l15;
        const float bias = b[j];
#pragma unroll
        for (int r = 0; r < 4; r++) {
            const int row = m0 + quad * 4 + r;
            const float val = acc[nt][r] + bias;
            if (j < 256) {
                Qb[((j >> 5) * L + row) * DH + (j & 31)] = f2bf(val * RS);
            } else if (j < 512) {
                const int jj = j - 256;
                const int srow = (row & ~63) + ksig(row & 63);
                Kb[((jj >> 5) * L + srow) * DH + (jj & 31)] = f2bf(val);
            } else {
                const int jj = j - 512;
                Vt[((jj >> 5) * DH + (jj & 31)) * L + row] = f2bf(val);
            }
        }
    }
}

// ---------------- Kernel 2: register-resident flash attention ----------------
// Depth-1 REGISTER prefetch of K/V/mask: moves all load latency one iteration back
// so the per-iter dependent chain is compute-only (R9 showed wall == one wave's
// serial chain; waves stall in lockstep, so the chain length IS the wall).
template<int KT>
__global__ __launch_bounds__(512) void attn_kernel(
        const ushort* __restrict__ Qb, const ushort* __restrict__ Kb,
        const ushort* __restrict__ Vt, const unsigned char* __restrict__ m2,
        const float* __restrict__ edge_bias,
        float* __restrict__ Opart, float* __restrict__ lpart)
{
    __shared__ float ebt[8 * 16 * 64];   // [h][e][lane] -> bank=lane%32, 2-way free

    const int tid = threadIdx.x;
    const int lane = tid & 63, h = tid >> 6;
    const int quad = lane >> 4, l15 = lane & 15;
    const int q0 = blockIdx.x * 16;
    const int ktbase = blockIdx.y * KT;

    {
        float* t = ebt + h * 1024 + lane;
#pragma unroll
        for (int e = 0; e < 16; e++)
            t[e * 64] = (e < 14) ? edge_bias[e * H + h] * LOG2E : 0.f;
    }
    asm volatile("s_waitcnt lgkmcnt(0)" ::: "memory");   // one-time, wave-private

    const bf16x8 qf = *(const bf16x8*)(Qb + (h * L + q0 + l15) * DH + quad * 8);
    const char* ebl = (const char*)(ebt + h * 1024 + lane);

    // per-lane base pointers
    const ushort* Kl = Kb + h * L * DH + ktbase * 64 * DH + l15 * DH + quad * 8;
    const ushort* Va = Vt + (h * DH + l15) * L + ktbase * 64 + quad * 8;
    const ushort* Vb = Vt + (h * DH + 16 + l15) * L + ktbase * 64 + quad * 8;
    const unsigned char* mp = m2 + (size_t)blockIdx.x * 65536
                            + (size_t)ktbase * 1024 + lane * 16;

    f32x4 o0 = {}, o1 = {}, osum = {};
    bf16x8 ones;
#pragma unroll
    for (int i = 0; i < 8; i++) ones[i] = (short)0x3F80;   // 1.0 bf16

    // ---- prologue: load iteration 0's operands ----
    int4 mwc = *(const int4*)mp;
    bf16x8 kc[4], vc[4];
#pragma unroll
    for (int nt = 0; nt < 4; nt++) kc[nt] = *(const bf16x8*)(Kl + nt * 512);
    vc[0] = *(const bf16x8*)(Va);
    vc[1] = *(const bf16x8*)(Vb);
    vc[2] = *(const bf16x8*)(Va + 32);
    vc[3] = *(const bf16x8*)(Vb + 32);

    for (int kt = 0; kt < KT; kt++) {
        // ---- prefetch iteration kt+1 (tail reads stay inside d_ws) ----
        const int4 mwn = *(const int4*)(mp + (kt + 1) * 1024);
        bf16x8 kn[4], vn[4];
#pragma unroll
        for (int nt = 0; nt < 4; nt++)
            kn[nt] = *(const bf16x8*)(Kl + (kt + 1) * 2048 + nt * 512);
        vn[0] = *(const bf16x8*)(Va + (kt + 1) * 64);
        vn[1] = *(const bf16x8*)(Vb + (kt + 1) * 64);
        vn[2] = *(const bf16x8*)(Va + (kt + 1) * 64 + 32);
        vn[3] = *(const bf16x8*)(Vb + (kt + 1) * 64 + 32);

        const unsigned int mwa[4] = {(unsigned int)mwc.x, (unsigned int)mwc.y,
                                     (unsigned int)mwc.z, (unsigned int)mwc.w};

        // ---- compute iteration kt (all operands already in registers) ----
#pragma unroll
        for (int half = 0; half < 2; half++) {
            union { bf16x8 v; unsigned int u[4]; } pf;
#pragma unroll
            for (int nt2 = 0; nt2 < 2; nt2++) {
                const int nt = half * 2 + nt2;
                f32x4 z = {};
                f32x4 sv = __builtin_amdgcn_mfma_f32_16x16x32_bf16(kc[nt], qf, z, 0, 0, 0);
                const unsigned int w = mwa[nt];
                float p0 = __builtin_amdgcn_exp2f(sv[0] + *(const float*)(ebl + ((w        & 255u) << 4)));
                float p1 = __builtin_amdgcn_exp2f(sv[1] + *(const float*)(ebl + (((w >> 8)  & 255u) << 4)));
                float p2 = __builtin_amdgcn_exp2f(sv[2] + *(const float*)(ebl + (((w >> 16) & 255u) << 4)));
                float p3 = __builtin_amdgcn_exp2f(sv[3] + *(const float*)(ebl + ((w >> 24)         << 4)));
                pf.u[nt2 * 2]     = pkbf(p0, p1);
                pf.u[nt2 * 2 + 1] = pkbf(p2, p3);
            }
            o0   = __builtin_amdgcn_mfma_f32_16x16x32_bf16(vc[half * 2],     pf.v, o0, 0, 0, 0);
            o1   = __builtin_amdgcn_mfma_f32_16x16x32_bf16(vc[half * 2 + 1], pf.v, o1, 0, 0, 0);
            osum = __builtin_amdgcn_mfma_f32_16x16x32_bf16(ones,             pf.v, osum, 0, 0, 0);
        }

        mwc = mwn;
#pragma unroll
        for (int nt = 0; nt < 4; nt++) { kc[nt] = kn[nt]; vc[nt] = vn[nt]; }
    }

    float* Op = Opart + (size_t)(blockIdx.y * 8 + h) * (L * 32) + (q0 + l15) * 32;
    float4 s0; s0.x = o0[0]; s0.y = o0[1]; s0.z = o0[2]; s0.w = o0[3];
    float4 s1; s1.x = o1[0]; s1.y = o1[1]; s1.z = o1[2]; s1.w = o1[3];
    *(float4*)(Op + quad * 4) = s0;
    *(float4*)(Op + 16 + quad * 4) = s1;
    if (quad == 0)
        lpart[(size_t)(blockIdx.y * 8 + h) * L + q0 + l15] = osum[0];
}

// ---------------- Kernel 3: fused finalize + output projection ----------------
// Builds the A-fragment (normalized attention output, bf16) directly from the
// split partials — removes the finalize kernel and the AO round-trip.
__global__ __launch_bounds__(256) void oproj_kernel(
        const float* __restrict__ Opart, const float* __restrict__ lpart,
        const ushort* __restrict__ wb, const float* __restrict__ b,
        float* __restrict__ out, int SP)
{
    const int lane = threadIdx.x & 63, wv = threadIdx.x >> 6;
    const int quad = lane >> 4, l15 = lane & 15;
    const int m0 = blockIdx.x * 64 + wv * 16;
    const int n0 = blockIdx.y * 64;
    const int row = m0 + l15;

    f32x4 acc[4] = {};
    for (int ks = 0; ks < 8; ks++) {          // ks == head for this 32-col chunk
        float4 a = {0.f, 0.f, 0.f, 0.f}, c = {0.f, 0.f, 0.f, 0.f};
        float l = 0.f;
        for (int s = 0; s < SP; s++) {
            const float* base = Opart + ((size_t)(s * 8 + ks) * L + row) * 32 + quad * 8;
            float4 u = *(const float4*)base;
            float4 w2 = *(const float4*)(base + 4);
            a.x += u.x; a.y += u.y; a.z += u.z; a.w += u.w;
            c.x += w2.x; c.y += w2.y; c.z += w2.z; c.w += w2.w;
            l += lpart[(size_t)(s * 8 + ks) * L + row];
        }
        const float inv = 1.f / l;
        union { bf16x8 v; unsigned int u[4]; } af;
        af.u[0] = pkbf(a.x * inv, a.y * inv);
        af.u[1] = pkbf(a.z * inv, a.w * inv);
        af.u[2] = pkbf(c.x * inv, c.y * inv);
        af.u[3] = pkbf(c.z * inv, c.w * inv);
#pragma unroll
        for (int nt = 0; nt < 4; nt++) {
            bf16x8 bfr = *(const bf16x8*)(wb + (n0 + nt * 16 + l15) * D + ks * 32 + quad * 8);
            acc[nt] = __builtin_amdgcn_mfma_f32_16x16x32_bf16(af.v, bfr, acc[nt], 0, 0, 0);
        }
    }
#pragma unroll
    for (int nt = 0; nt < 4; nt++) {
        const int j = n0 + nt * 16 + l15;
        const float bias = b[j];
#pragma unroll
        for (int r = 0; r < 4; r++) {
            const int orow = m0 + quad * 4 + r;
            out[orow * D + j] = acc[nt][r] + bias;
        }
    }
}

extern "C" void kernel_launch(void* const* d_in, const int* in_sizes, int n_in,
                              void* d_out, int out_size, void* d_ws, size_t ws_size,
                              hipStream_t stream) {
    const float* x     = (const float*)d_in[0];
    const int*   mask  = (const int*)d_in[1];
    const float* in_w  = (const float*)d_in[2];
    const float* in_b  = (const float*)d_in[3];
    const float* out_w = (const float*)d_in[4];
    const float* out_b = (const float*)d_in[5];
    const float* eb    = (const float*)d_in[6];

    ushort* ws = (ushort*)d_ws;
    ushort* Qb  = ws;
    ushort* Kb  = Qb + H * L * DH;             // sigma-permuted rows
    ushort* Vt  = Kb + H * L * DH;
    ushort* xb  = Vt + H * L * DH;             // x bf16 (qkv staging)
    ushort* wib = xb + L * D;
    ushort* wob = wib + 3 * D * D;
    unsigned char* m2 = (unsigned char*)(wob + D * D);           // 16 MB e<<4 stream
    float* Opart = (float*)(m2 + (size_t)L * L);
    int SP = (ws_size >= (size_t)25690112 + 4u * 4325376u) ? 4
           : (ws_size >= (size_t)25690112 + 2u * 4325376u) ? 2 : 1;
    float* lpart = Opart + (size_t)SP * H * L * DH;
    float* out = (float*)d_out;

    pack_kernel<<<dim3(1152), 256, 0, stream>>>(mask, x, in_w, out_w,
                                                (unsigned int*)m2, xb, wib, wob);
    qkv_kernel<<<dim3(64, 12), 256, 0, stream>>>(xb, wib, in_b, Qb, Kb, Vt);
    if (SP == 4)
        attn_kernel<16><<<dim3(256, 4), 512, 0, stream>>>(Qb, Kb, Vt, m2, eb, Opart, lpart);
    else if (SP == 2)
        attn_kernel<32><<<dim3(256, 2), 512, 0, stream>>>(Qb, Kb, Vt, m2, eb, Opart, lpart);
    else
        attn_kernel<64><<<dim3(256, 1), 512, 0, stream>>>(Qb, Kb, Vt, m2, eb, Opart, lpart);
    oproj_kernel<<<dim3(64, 4), 256, 0, stream>>>(Opart, lpart, wob, out_b, out, SP);
}

// Round 11
// 203.694 us; speedup vs baseline: 1.2055x; 1.2055x over previous
//
#include <hip/hip_runtime.h>
#include <hip/hip_bf16.h>
#include <string.h>

#define L 4096
#define D 256
#define H 8
#define DH 32

typedef __attribute__((ext_vector_type(8))) short bf16x8;
typedef __attribute__((ext_vector_type(4))) float f32x4;

#define LOG2E 1.4426950408889634f
#define RS (0.17677669529663688f * LOG2E)   // 1/sqrt(DH) * log2(e), folded into Q

__device__ __forceinline__ ushort f2bf(float f) {
    union { float f; unsigned int i; } v; v.f = f;
    unsigned int x = v.i;
    return (ushort)((x + 0x7fffu + ((x >> 16) & 1u)) >> 16);   // RNE
}
__device__ __forceinline__ bf16x8 cvt8(const float* p) {
    float4 a = *(const float4*)p;
    float4 b = *(const float4*)(p + 4);
    bf16x8 r;
    r[0] = (short)f2bf(a.x); r[1] = (short)f2bf(a.y);
    r[2] = (short)f2bf(a.z); r[3] = (short)f2bf(a.w);
    r[4] = (short)f2bf(b.x); r[5] = (short)f2bf(b.y);
    r[6] = (short)f2bf(b.z); r[7] = (short)f2bf(b.w);
    return r;
}
// pack two fp32 -> bf16x2 dword; native v_cvt_pk_bf16_f32 on gfx950
__device__ __forceinline__ unsigned int pkbf(float a, float b) {
    float2 t; t.x = a; t.y = b;
    __hip_bfloat162 r = __float22bfloat162_rn(t);
    unsigned int u; memcpy(&u, &r, 4);
    return u;
}

// sigma: logical key u (0..63) -> K storage row within its 64-block.
__device__ __forceinline__ int ksig(int u) {
    return 32 * (u >> 5) + 16 * ((u >> 2) & 1) + 4 * ((u >> 3) & 3) + (u & 3);
}

// ---------------- Kernel 0: prepack ----------------
__global__ __launch_bounds__(256) void pack_kernel(
        const int* __restrict__ mask, const float* __restrict__ x,
        const float* __restrict__ wi, const float* __restrict__ wo,
        unsigned int* __restrict__ m2, ushort* __restrict__ xb,
        ushort* __restrict__ wib, ushort* __restrict__ wob)
{
    const int b = blockIdx.x;
    const int tid = threadIdx.x;
    if (b < 512) {
        __shared__ unsigned int rb[8 * 1025];
        const int4* src = (const int4*)(mask + (size_t)b * 8 * 4096);
#pragma unroll
        for (int i = 0; i < 32; i++) {
            const int g = i * 256 + tid;
            int4 v = src[g];
            rb[(g >> 10) * 1025 + (g & 1023)] =
                ((unsigned int)(v.x & 15) << 4)  | ((unsigned int)(v.y & 15) << 12) |
                ((unsigned int)(v.z & 15) << 20) | ((unsigned int)(v.w & 15) << 28);
        }
        __syncthreads();
        const int t = b >> 1, half = b & 1;
#pragma unroll
        for (int i = 0; i < 32; i++) {
            const int dd = i * 256 + tid;
            const int nt = dd & 3, s = (dd >> 2) & 7, qd = (dd >> 5) & 3, kt = dd >> 7;
            const unsigned int w =
                rb[s * 1025 + kt * 16 + 8 * (nt >> 1) + 2 * qd + (nt & 1)];
            m2[(size_t)t * 16384 + kt * 256 + (qd * 16 + 8 * half + s) * 4 + nt] = w;
        }
    } else if (b < 1024) {
        const int t = (b - 512) * 256 + tid;
        ((bf16x8*)xb)[t] = cvt8(x + t * 8);
    } else if (b < 1120) {
        const int t = (b - 1024) * 256 + tid;
        ((bf16x8*)wib)[t] = cvt8(wi + t * 8);
    } else {
        const int t = (b - 1120) * 256 + tid;
        ((bf16x8*)wob)[t] = cvt8(wo + t * 8);
    }
}

// ---------------- Kernel 1: QKV projection ----------------
__global__ __launch_bounds__(256) void qkv_kernel(
        const ushort* __restrict__ xb, const ushort* __restrict__ wb,
        const float* __restrict__ b,
        ushort* __restrict__ Qb, ushort* __restrict__ Kb, ushort* __restrict__ Vt)
{
    const int lane = threadIdx.x & 63, wv = threadIdx.x >> 6;
    const int quad = lane >> 4, l15 = lane & 15;
    const int m0 = blockIdx.x * 64 + wv * 16;
    const int n0 = blockIdx.y * 64;

    f32x4 acc[4] = {};
    for (int ks = 0; ks < 8; ks++) {
        const int kd = ks * 32 + quad * 8;
        bf16x8 af = *(const bf16x8*)(xb + (m0 + l15) * D + kd);
#pragma unroll
        for (int nt = 0; nt < 4; nt++) {
            bf16x8 bfr = *(const bf16x8*)(wb + (n0 + nt * 16 + l15) * D + kd);
            acc[nt] = __builtin_amdgcn_mfma_f32_16x16x32_bf16(af, bfr, acc[nt], 0, 0, 0);
        }
    }
#pragma unroll
    for (int nt = 0; nt < 4; nt++) {
        const int j = n0 + nt * 16 + l15;
        const float bias = b[j];
#pragma unroll
        for (int r = 0; r < 4; r++) {
            const int row = m0 + quad * 4 + r;
            const float val = acc[nt][r] + bias;
            if (j < 256) {
                Qb[((j >> 5) * L + row) * DH + (j & 31)] = f2bf(val * RS);
            } else if (j < 512) {
                const int jj = j - 256;
                const int srow = (row & ~63) + ksig(row & 63);
                Kb[((jj >> 5) * L + srow) * DH + (jj & 31)] = f2bf(val);
            } else {
                const int jj = j - 512;
                Vt[((jj >> 5) * DH + (jj & 31)) * L + row] = f2bf(val);
            }
        }
    }
}

// ---------------- Kernel 2: register-resident flash attention, 2 q-tiles/wave ----------------
// R8-R10 showed: occupancy-insensitive, prefetch-insensitive, all pipes <35% => ILP-starved.
// Two independent q-tile chains per wave (shared K/V loads) double per-wave ILP and
// per-loaded-byte compute. No manual prefetch (compiler hoists; R10 proved manual hurts).
template<int KT>
__global__ __launch_bounds__(512) void attn_kernel(
        const ushort* __restrict__ Qb, const ushort* __restrict__ Kb,
        const ushort* __restrict__ Vt, const unsigned char* __restrict__ m2,
        const float* __restrict__ edge_bias,
        float* __restrict__ Opart, float* __restrict__ lpart)
{
    __shared__ float ebt[8 * 16 * 64];   // [h][e][lane] -> bank=lane%32, 2-way free

    const int tid = threadIdx.x;
    const int lane = tid & 63, h = tid >> 6;
    const int quad = lane >> 4, l15 = lane & 15;
    const int q0 = blockIdx.x * 32;          // this block: q-tiles q0 and q0+16
    const int ktbase = blockIdx.y * KT;

    {
        float* t = ebt + h * 1024 + lane;
#pragma unroll
        for (int e = 0; e < 16; e++)
            t[e * 64] = (e < 14) ? edge_bias[e * H + h] * LOG2E : 0.f;
    }
    asm volatile("s_waitcnt lgkmcnt(0)" ::: "memory");   // one-time, wave-private

    const bf16x8 qfA = *(const bf16x8*)(Qb + (h * L + q0 + l15) * DH + quad * 8);
    const bf16x8 qfB = *(const bf16x8*)(Qb + (h * L + q0 + 16 + l15) * DH + quad * 8);
    const char* ebl = (const char*)(ebt + h * 1024 + lane);

    const ushort* Kl = Kb + h * L * DH + ktbase * 64 * DH + l15 * DH + quad * 8;
    const ushort* Va = Vt + (h * DH + l15) * L + ktbase * 64 + quad * 8;
    const ushort* Vb = Vt + (h * DH + 16 + l15) * L + ktbase * 64 + quad * 8;
    const unsigned char* mpA = m2 + (size_t)(2 * blockIdx.x) * 65536
                             + (size_t)ktbase * 1024 + lane * 16;
    const unsigned char* mpB = mpA + 65536;

    f32x4 o0A = {}, o1A = {}, osA = {};
    f32x4 o0B = {}, o1B = {}, osB = {};
    bf16x8 ones;
#pragma unroll
    for (int i = 0; i < 8; i++) ones[i] = (short)0x3F80;   // 1.0 bf16

    for (int kt = 0; kt < KT; kt++) {
        const int4 mA4 = *(const int4*)(mpA + kt * 1024);
        const int4 mB4 = *(const int4*)(mpB + kt * 1024);
        const unsigned int mA[4] = {(unsigned int)mA4.x, (unsigned int)mA4.y,
                                    (unsigned int)mA4.z, (unsigned int)mA4.w};
        const unsigned int mB[4] = {(unsigned int)mB4.x, (unsigned int)mB4.y,
                                    (unsigned int)mB4.z, (unsigned int)mB4.w};

#pragma unroll
        for (int half = 0; half < 2; half++) {
            union { bf16x8 v; unsigned int u[4]; } pfA, pfB;
#pragma unroll
            for (int nt2 = 0; nt2 < 2; nt2++) {
                const int nt = half * 2 + nt2;
                bf16x8 kf = *(const bf16x8*)(Kl + (kt * 64 + nt * 16) * DH);
                f32x4 z = {};
                f32x4 svA = __builtin_amdgcn_mfma_f32_16x16x32_bf16(kf, qfA, z, 0, 0, 0);
                f32x4 svB = __builtin_amdgcn_mfma_f32_16x16x32_bf16(kf, qfB, z, 0, 0, 0);
                const unsigned int wA = mA[nt], wB = mB[nt];
                float a0 = __builtin_amdgcn_exp2f(svA[0] + *(const float*)(ebl + ((wA        & 255u) << 4)));
                float a1 = __builtin_amdgcn_exp2f(svA[1] + *(const float*)(ebl + (((wA >> 8)  & 255u) << 4)));
                float a2 = __builtin_amdgcn_exp2f(svA[2] + *(const float*)(ebl + (((wA >> 16) & 255u) << 4)));
                float a3 = __builtin_amdgcn_exp2f(svA[3] + *(const float*)(ebl + ((wA >> 24)         << 4)));
                float b0 = __builtin_amdgcn_exp2f(svB[0] + *(const float*)(ebl + ((wB        & 255u) << 4)));
                float b1 = __builtin_amdgcn_exp2f(svB[1] + *(const float*)(ebl + (((wB >> 8)  & 255u) << 4)));
                float b2 = __builtin_amdgcn_exp2f(svB[2] + *(const float*)(ebl + (((wB >> 16) & 255u) << 4)));
                float b3 = __builtin_amdgcn_exp2f(svB[3] + *(const float*)(ebl + ((wB >> 24)         << 4)));
                pfA.u[nt2 * 2]     = pkbf(a0, a1);
                pfA.u[nt2 * 2 + 1] = pkbf(a2, a3);
                pfB.u[nt2 * 2]     = pkbf(b0, b1);
                pfB.u[nt2 * 2 + 1] = pkbf(b2, b3);
            }
            bf16x8 va = *(const bf16x8*)(Va + kt * 64 + half * 32);
            bf16x8 vb = *(const bf16x8*)(Vb + kt * 64 + half * 32);
            o0A = __builtin_amdgcn_mfma_f32_16x16x32_bf16(va,   pfA.v, o0A, 0, 0, 0);
            o1A = __builtin_amdgcn_mfma_f32_16x16x32_bf16(vb,   pfA.v, o1A, 0, 0, 0);
            osA = __builtin_amdgcn_mfma_f32_16x16x32_bf16(ones, pfA.v, osA, 0, 0, 0);
            o0B = __builtin_amdgcn_mfma_f32_16x16x32_bf16(va,   pfB.v, o0B, 0, 0, 0);
            o1B = __builtin_amdgcn_mfma_f32_16x16x32_bf16(vb,   pfB.v, o1B, 0, 0, 0);
            osB = __builtin_amdgcn_mfma_f32_16x16x32_bf16(ones, pfB.v, osB, 0, 0, 0);
        }
    }

    float* OpA = Opart + (size_t)(blockIdx.y * 8 + h) * (L * 32) + (q0 + l15) * 32;
    float* OpB = OpA + 16 * 32;
    float4 s;
    s.x = o0A[0]; s.y = o0A[1]; s.z = o0A[2]; s.w = o0A[3]; *(float4*)(OpA + quad * 4) = s;
    s.x = o1A[0]; s.y = o1A[1]; s.z = o1A[2]; s.w = o1A[3]; *(float4*)(OpA + 16 + quad * 4) = s;
    s.x = o0B[0]; s.y = o0B[1]; s.z = o0B[2]; s.w = o0B[3]; *(float4*)(OpB + quad * 4) = s;
    s.x = o1B[0]; s.y = o1B[1]; s.z = o1B[2]; s.w = o1B[3]; *(float4*)(OpB + 16 + quad * 4) = s;
    if (quad == 0) {
        lpart[(size_t)(blockIdx.y * 8 + h) * L + q0 + l15] = osA[0];
        lpart[(size_t)(blockIdx.y * 8 + h) * L + q0 + 16 + l15] = osB[0];
    }
}

// ---------------- Kernel 3: fused finalize + output projection ----------------
__global__ __launch_bounds__(256) void oproj_kernel(
        const float* __restrict__ Opart, const float* __restrict__ lpart,
        const ushort* __restrict__ wb, const float* __restrict__ b,
        float* __restrict__ out, int SP)
{
    const int lane = threadIdx.x & 63, wv = threadIdx.x >> 6;
    const int quad = lane >> 4, l15 = lane & 15;
    const int m0 = blockIdx.x * 64 + wv * 16;
    const int n0 = blockIdx.y * 64;
    const int row = m0 + l15;

    f32x4 acc[4] = {};
    for (int ks = 0; ks < 8; ks++) {          // ks == head for this 32-col chunk
        float4 a = {0.f, 0.f, 0.f, 0.f}, c = {0.f, 0.f, 0.f, 0.f};
        float l = 0.f;
        for (int s = 0; s < SP; s++) {
            const float* base = Opart + ((size_t)(s * 8 + ks) * L + row) * 32 + quad * 8;
            float4 u = *(const float4*)base;
            float4 w2 = *(const float4*)(base + 4);
            a.x += u.x; a.y += u.y; a.z += u.z; a.w += u.w;
            c.x += w2.x; c.y += w2.y; c.z += w2.z; c.w += w2.w;
            l += lpart[(size_t)(s * 8 + ks) * L + row];
        }
        const float inv = 1.f / l;
        union { bf16x8 v; unsigned int u[4]; } af;
        af.u[0] = pkbf(a.x * inv, a.y * inv);
        af.u[1] = pkbf(a.z * inv, a.w * inv);
        af.u[2] = pkbf(c.x * inv, c.y * inv);
        af.u[3] = pkbf(c.z * inv, c.w * inv);
#pragma unroll
        for (int nt = 0; nt < 4; nt++) {
            bf16x8 bfr = *(const bf16x8*)(wb + (n0 + nt * 16 + l15) * D + ks * 32 + quad * 8);
            acc[nt] = __builtin_amdgcn_mfma_f32_16x16x32_bf16(af.v, bfr, acc[nt], 0, 0, 0);
        }
    }
#pragma unroll
    for (int nt = 0; nt < 4; nt++) {
        const int j = n0 + nt * 16 + l15;
        const float bias = b[j];
#pragma unroll
        for (int r = 0; r < 4; r++) {
            const int orow = m0 + quad * 4 + r;
            out[orow * D + j] = acc[nt][r] + bias;
        }
    }
}

extern "C" void kernel_launch(void* const* d_in, const int* in_sizes, int n_in,
                              void* d_out, int out_size, void* d_ws, size_t ws_size,
                              hipStream_t stream) {
    const float* x     = (const float*)d_in[0];
    const int*   mask  = (const int*)d_in[1];
    const float* in_w  = (const float*)d_in[2];
    const float* in_b  = (const float*)d_in[3];
    const float* out_w = (const float*)d_in[4];
    const float* out_b = (const float*)d_in[5];
    const float* eb    = (const float*)d_in[6];

    ushort* ws = (ushort*)d_ws;
    ushort* Qb  = ws;
    ushort* Kb  = Qb + H * L * DH;             // sigma-permuted rows
    ushort* Vt  = Kb + H * L * DH;
    ushort* xb  = Vt + H * L * DH;             // x bf16 (qkv staging)
    ushort* wib = xb + L * D;
    ushort* wob = wib + 3 * D * D;
    unsigned char* m2 = (unsigned char*)(wob + D * D);           // 16 MB e<<4 stream
    float* Opart = (float*)(m2 + (size_t)L * L);
    int SP = (ws_size >= (size_t)25690112 + 4u * 4325376u) ? 4
           : (ws_size >= (size_t)25690112 + 2u * 4325376u) ? 2 : 1;
    float* lpart = Opart + (size_t)SP * H * L * DH;
    float* out = (float*)d_out;

    pack_kernel<<<dim3(1152), 256, 0, stream>>>(mask, x, in_w, out_w,
                                                (unsigned int*)m2, xb, wib, wob);
    qkv_kernel<<<dim3(64, 12), 256, 0, stream>>>(xb, wib, in_b, Qb, Kb, Vt);
    if (SP == 4)
        attn_kernel<16><<<dim3(128, 4), 512, 0, stream>>>(Qb, Kb, Vt, m2, eb, Opart, lpart);
    else if (SP == 2)
        attn_kernel<32><<<dim3(128, 2), 512, 0, stream>>>(Qb, Kb, Vt, m2, eb, Opart, lpart);
    else
        attn_kernel<64><<<dim3(128, 1), 512, 0, stream>>>(Qb, Kb, Vt, m2, eb, Opart, lpart);
    oproj_kernel<<<dim3(64, 4), 256, 0, stream>>>(Opart, lpart, wob, out_b, out, SP);
}